// Round 13
// baseline (406.622 us; speedup 1.0000x reference)
//
#include <hip/hip_runtime.h>
#include <hip/hip_cooperative_groups.h>
#include <hip/hip_bf16.h>
#include <stdint.h>

namespace cg = cooperative_groups;

// WSVectorQuantizer: N=65536 rows (D=256) vs K=1024 codewords.
// v17: ONE cooperative dispatch (512x256, 2 blocks/CU -- exactly co-resident).
// Phases: A prep(blocks 0-255) || A-frag z loads(all) ; sync ; B v13-proven
// chunk loop + classify-only epilogue ; sync ; C resolve patches idx+hist ;
// sync ; D full-parallel gather from FINAL idx (+stats on block 0).
// Rationale (v15/v16 evidence): per-dispatch fixed cost ~15-25us each, and
// v16's tail-fused gather cost 43us vs ~25us as a streaming phase.
// Fallback to v16's 4-dispatch path if cooperative enqueue fails.

typedef float  v4f __attribute__((ext_vector_type(4)));
typedef _Float16 v8h __attribute__((ext_vector_type(8)));
typedef _Float16 v4h __attribute__((ext_vector_type(4)));

#define N_ROWS 65536
#define N_DICT 1024
#define DIMS   256
#define MARGIN 4e-3f   // ~10x worst-tail of split-fp16 error (~4e-4)

__device__ __forceinline__ void gl_lds16(const void* g, void* l) {
  __builtin_amdgcn_global_load_lds(
      (const __attribute__((address_space(1))) unsigned int*)g,
      (__attribute__((address_space(3))) unsigned int*)l,
      16, 0, 0);
}

// ---------------- fused cooperative kernel ----------------
__launch_bounds__(256, 2)
__global__ void k_fused(const float* __restrict__ z, const float* __restrict__ cb,
                        _Float16* __restrict__ swz_h, _Float16* __restrict__ swz_l,
                        float* __restrict__ cnA, double* __restrict__ cnD,
                        float* __restrict__ outz, unsigned* __restrict__ out_idx,
                        unsigned long long* __restrict__ list1,
                        unsigned* __restrict__ list2,
                        unsigned* __restrict__ hist, unsigned* __restrict__ counters) {
  cg::grid_group grid = cg::this_grid();
  __shared__ __align__(16) char lds[2][32768];
  __shared__ float lds_cn[N_DICT];
  __shared__ double sc[4];
  __shared__ int scc[4];
  __shared__ float ls[4];

  const int t = threadIdx.x, lane = t & 63, w = t >> 6;
  const int l15 = lane & 15, q = lane >> 4;
  const int bid = blockIdx.x;
  const int waverow = (bid * 4 + w) * 32;

  // ======== Phase A: prep (blocks 0-255) + A-frag loads (all blocks) ======
  if (bid < 256) {
    if (bid == 0) {
      for (int i = t; i < N_DICT; i += 256) hist[i] = 0u;
      if (t == 0) { counters[0] = 0u; counters[1] = 0u; }
    }
    const int gid = bid * 256 + t;             // 65536 threads x 4 elems
    const int col = gid >> 6;
    const int k0  = (gid & 63) * 4;
    v4f v = ((const v4f*)cb)[gid];
    v4h h, l;
    #pragma unroll
    for (int j = 0; j < 4; ++j) {
      h[j] = (_Float16)v[j];
      float r = v[j] - (float)h[j];            // exact residual
      l[j] = (_Float16)r;                      // |err| <= 2^-22 |v|
    }
    const int c = col >> 6, t4 = (col >> 4) & 3, cl = col & 15;
    const int kk = k0 >> 5, qq = (k0 >> 3) & 3, j0 = k0 & 7;
    const size_t off = (size_t)(((c * 8 + kk) * 4 + t4) * 512 + (qq * 16 + cl) * 8 + j0);
    *(v4h*)(swz_h + off) = h;
    *(v4h*)(swz_l + off) = l;
    // exact ||c||^2 (fp64 acc): one wave per codeword
    const int crow = bid * 4 + w;
    v4f u = ((const v4f*)cb)[crow * 64 + lane];
    double s = (double)u[0]*u[0] + (double)u[1]*u[1]
             + (double)u[2]*u[2] + (double)u[3]*u[3];
    #pragma unroll
    for (int d = 1; d < 64; d <<= 1) s += __shfl_xor(s, d);
    if (lane == 0) { cnA[crow] = (float)s; cnD[crow] = s; }
  }

  // A fragments: lane holds z[waverow+m*16+l15][kk*32 + q*8 .. +8], split h/l
  v8h ah[2][8], al[2][8];
  #pragma unroll
  for (int m = 0; m < 2; ++m) {
    const float* zp = z + (size_t)(waverow + m * 16 + l15) * DIMS + q * 8;
    #pragma unroll
    for (int kk = 0; kk < 8; ++kk) {
      v4f f0 = *(const v4f*)(zp + kk * 32);
      v4f f1 = *(const v4f*)(zp + kk * 32 + 4);
      v8h hh, ll;
      #pragma unroll
      for (int j = 0; j < 4; ++j) {
        hh[j] = (_Float16)f0[j];
        float r = f0[j] - (float)hh[j];
        ll[j] = (_Float16)r;
        hh[4 + j] = (_Float16)f1[j];
        r = f1[j] - (float)hh[4 + j];
        ll[4 + j] = (_Float16)r;
      }
      ah[m][kk] = hh; al[m][kk] = ll;
    }
  }

  grid.sync();   // swz, cnA/cnD, hist, counters now visible grid-wide

  // ======== Phase B: main split-fp16 MFMA chunk loop (v13-proven) =========
  for (int i = t; i < N_DICT; i += 256) lds_cn[i] = cnA[i];

  // Staging: wave w owns LDS streams s = w*8 .. w*8+7 (s = hl*16 + kk*2 + u).
  // Chunk n (32 cols): c = n>>1, half = n&1, t4 = 2*half + u.
  // Global src: hl_base + c*32768 + kk*4096 + (2*half+u)*1024 + lane*16.
  const int s0 = w * 8;
  const char* gsrc_base = (const char*)(s0 >= 16 ? swz_l : swz_h);

  float m1[8], m2[8], m3[8]; int c1[8], c2[8];
  #pragma unroll
  for (int s = 0; s < 8; ++s) {
    m1[s] = 1e30f; m2[s] = 1e30f; m3[s] = 1e30f; c1[s] = 0; c2[s] = 0;
  }

  // prologue: stage chunk 0 into lds[0]
  #pragma unroll
  for (int i = 0; i < 8; ++i) {
    const int s = s0 + i, kk = (s >> 1) & 7, u = s & 1;
    const char* gb = gsrc_base + (size_t)(kk * 4096 + u * 1024 + lane * 16);
    gl_lds16(gb, &lds[0][s * 1024]);
  }
  __syncthreads();   // drains prologue staging + lds_cn writes

  for (int cc = 0; cc < 32; ++cc) {
    if (cc + 1 < 32) {
      const int n = cc + 1, c = n >> 1, half = n & 1;
      char* nbuf = lds[n & 1];
      #pragma unroll
      for (int i = 0; i < 8; ++i) {
        const int s = s0 + i, kk = (s >> 1) & 7, u = s & 1;
        const char* gb = gsrc_base +
            (size_t)(c * 32768 + kk * 4096 + (2 * half + u) * 1024 + lane * 16);
        gl_lds16(gb, nbuf + s * 1024);
      }
    }

    const char* buf = lds[cc & 1];
    const int c = cc >> 1, half = cc & 1;
    const int n0 = c * 64 + half * 32;
    float cn[2]; int colv[2];
    #pragma unroll
    for (int u = 0; u < 2; ++u) {
      colv[u] = n0 + u * 16 + l15;
      cn[u] = lds_cn[colv[u]];
    }
    v4f acc[2][2];
    #pragma unroll
    for (int m = 0; m < 2; ++m)
      #pragma unroll
      for (int u = 0; u < 2; ++u) acc[m][u] = (v4f){0.f, 0.f, 0.f, 0.f};

    #pragma unroll
    for (int kk = 0; kk < 8; ++kk) {
      v8h b_h[2], b_l[2];
      #pragma unroll
      for (int u = 0; u < 2; ++u)
        b_h[u] = *(const v8h*)(buf + (kk * 2 + u) * 1024 + lane * 16);
      #pragma unroll
      for (int u = 0; u < 2; ++u)
        b_l[u] = *(const v8h*)(buf + 16384 + (kk * 2 + u) * 1024 + lane * 16);
      #pragma unroll
      for (int m = 0; m < 2; ++m) {
        #pragma unroll
        for (int u = 0; u < 2; ++u)
          acc[m][u] = __builtin_amdgcn_mfma_f32_16x16x32_f16(ah[m][kk], b_h[u], acc[m][u], 0, 0, 0);
        #pragma unroll
        for (int u = 0; u < 2; ++u)
          acc[m][u] = __builtin_amdgcn_mfma_f32_16x16x32_f16(al[m][kk], b_h[u], acc[m][u], 0, 0, 0);
        #pragma unroll
        for (int u = 0; u < 2; ++u)
          acc[m][u] = __builtin_amdgcn_mfma_f32_16x16x32_f16(ah[m][kk], b_l[u], acc[m][u], 0, 0, 0);
      }
    }
    // top-3 update (ordered: m3 uses old m2; m2/c2 use old m1/c1)
    #pragma unroll
    for (int m = 0; m < 2; ++m)
      #pragma unroll
      for (int u = 0; u < 2; ++u)
        #pragma unroll
        for (int r = 0; r < 4; ++r) {
          float cost = fmaf(acc[m][u][r], -2.0f, cn[u]);
          const int s = m * 4 + r;
          bool lt1 = cost < m1[s];
          bool lt2 = cost < m2[s];
          bool lt3 = cost < m3[s];
          m3[s] = lt2 ? m2[s] : (lt3 ? cost : m3[s]);
          m2[s] = lt1 ? m1[s] : (lt2 ? cost : m2[s]);
          c2[s] = lt1 ? c1[s] : (lt2 ? colv[u] : c2[s]);
          m1[s] = lt1 ? cost : m1[s];
          c1[s] = lt1 ? colv[u] : c1[s];
        }
    __syncthreads();
  }

  // butterfly merge of sorted top-3 lists over the 16 lanes sharing q
  #pragma unroll
  for (int d = 1; d < 16; d <<= 1) {
    #pragma unroll
    for (int s = 0; s < 8; ++s) {
      float om1 = __shfl_xor(m1[s], d);
      float om2 = __shfl_xor(m2[s], d);
      float om3 = __shfl_xor(m3[s], d);
      int   oc1 = __shfl_xor(c1[s], d);
      int   oc2 = __shfl_xor(c2[s], d);
      bool take = (om1 < m1[s]) || (om1 == m1[s] && oc1 < c1[s]);
      float w1 = take ? om1 : m1[s];  int wc1 = take ? oc1 : c1[s];
      float w2 = take ? om2 : m2[s];  int wc2 = take ? oc2 : c2[s];
      float w3 = take ? om3 : m3[s];
      float l1 = take ? m1[s] : om1;  int lc1 = take ? c1[s] : oc1;
      float l2 = take ? m2[s] : om2;
      bool t2 = (l1 < w2) || (l1 == w2 && lc1 < wc2);
      m1[s] = w1; c1[s] = wc1;
      m2[s] = t2 ? l1 : w2;
      c2[s] = t2 ? lc1 : wc2;
      m3[s] = t2 ? fminf(w2, l2) : fminf(w3, l1);
    }
  }
  // classify-only epilogue (no gather here)
  if (l15 < 8) {
    const int s = l15, m = s >> 2, r = s & 3;
    const int row = waverow + m * 16 + q * 4 + r;
    const unsigned id = (unsigned)c1[s];
    out_idx[row] = id;
    atomicAdd(hist + id, 1u);
    if (m3[s] - m1[s] < MARGIN) {              // deep ambiguity: full scan
      unsigned pos = atomicAdd(&counters[1], 1u);
      list2[pos] = (unsigned)row;
    } else if (m2[s] - m1[s] < MARGIN) {       // only {c1,c2} can win
      unsigned pos = atomicAdd(&counters[0], 1u);
      list1[pos] = (unsigned long long)row
                 | ((unsigned long long)id << 20)
                 | ((unsigned long long)(unsigned)c2[s] << 40);
    }
  }

  grid.sync();   // idx, hist, lists, counters visible grid-wide

  // ======== Phase C: exact fp64 resolve (patch idx + hist) ================
  {
    // pair: wave per row; lanes 0-31 cost(c1), lanes 32-63 cost(c2)
    const unsigned count = counters[0];
    const unsigned gw = bid * 4 + w;
    const int half = lane >> 5, l5 = lane & 31;
    for (unsigned g = gw; g < count; g += 2048) {
      const unsigned long long e = list1[g];
      const unsigned row = (unsigned)(e & 0xFFFFFu);
      const int cc1 = (int)((e >> 20) & 0x3FFu);
      const int cc2 = (int)((e >> 40) & 0x3FFu);
      const int col = half ? cc2 : cc1;
      const float* cp = cb + (size_t)col * DIMS + l5 * 8;
      const float* zr = z + (size_t)row * DIMS + l5 * 8;
      v4f z0 = *(const v4f*)zr,  z1 = *(const v4f*)(zr + 4);
      v4f cc0 = *(const v4f*)cp, ccv = *(const v4f*)(cp + 4);
      double a = (double)z0[0] * (double)cc0[0];
      a = fma((double)z0[1], (double)cc0[1], a);
      a = fma((double)z0[2], (double)cc0[2], a);
      a = fma((double)z0[3], (double)cc0[3], a);
      a = fma((double)z1[0], (double)ccv[0], a);
      a = fma((double)z1[1], (double)ccv[1], a);
      a = fma((double)z1[2], (double)ccv[2], a);
      a = fma((double)z1[3], (double)ccv[3], a);
      #pragma unroll
      for (int d = 1; d < 32; d <<= 1) a += __shfl_xor(a, d);
      double cost = cnD[col] - 2.0 * a;
      double oc = __shfl_xor(cost, 32);
      if (lane == 0) {
        bool take = (oc < cost) || (oc == cost && cc2 < cc1);  // np lowest-index
        if (take) {                           // phase B wrote cc1; patch
          out_idx[row] = (unsigned)cc2;
          atomicAdd(hist + cc2, 1u);
          atomicAdd(hist + cc1, 0xFFFFFFFFu);
        }
      }
    }
    // deep: block per row; wave w covers ci = 4w..4w+3 (256 cols)
    const unsigned count2 = counters[1];
    for (unsigned g = bid; g < count2; g += 512) {
      const unsigned row = list2[g];
      const float* zr = z + (size_t)row * DIMS;
      double best = 1e300; int bc = 1 << 30;
      for (int ci = w * 4; ci < w * 4 + 4; ++ci) {
        const int col = ci * 64 + lane;
        const float* cp = cb + (size_t)col * DIMS;
        double a0 = 0, a1 = 0, a2 = 0, a3 = 0, a4 = 0, a5 = 0, a6 = 0, a7 = 0;
        #pragma unroll 8
        for (int k = 0; k < DIMS; k += 8) {
          v4f z0 = *(const v4f*)(zr + k);
          v4f z1 = *(const v4f*)(zr + k + 4);
          v4f cc0 = *(const v4f*)(cp + k);
          v4f cc1v = *(const v4f*)(cp + k + 4);
          a0 = fma((double)z0[0], (double)cc0[0], a0);
          a1 = fma((double)z0[1], (double)cc0[1], a1);
          a2 = fma((double)z0[2], (double)cc0[2], a2);
          a3 = fma((double)z0[3], (double)cc0[3], a3);
          a4 = fma((double)z1[0], (double)cc1v[0], a4);
          a5 = fma((double)z1[1], (double)cc1v[1], a5);
          a6 = fma((double)z1[2], (double)cc1v[2], a6);
          a7 = fma((double)z1[3], (double)cc1v[3], a7);
        }
        double cost = cnD[col]
                    - 2.0 * (((a0 + a1) + (a2 + a3)) + ((a4 + a5) + (a6 + a7)));
        if (cost < best || (cost == best && col < bc)) { best = cost; bc = col; }
      }
      #pragma unroll
      for (int d = 1; d < 64; d <<= 1) {
        double ob = __shfl_xor(best, d);
        int    oc = __shfl_xor(bc, d);
        if (ob < best || (ob == best && oc < bc)) { best = ob; bc = oc; }
      }
      if (lane == 0) { sc[w] = best; scc[w] = bc; }
      __syncthreads();
      if (t == 0) {
        double b = sc[0]; int c = scc[0];
        #pragma unroll
        for (int i = 1; i < 4; ++i)
          if (sc[i] < b || (sc[i] == b && scc[i] < c)) { b = sc[i]; c = scc[i]; }
        unsigned old = out_idx[row];
        if ((unsigned)c != old) {
          out_idx[row] = (unsigned)c;
          atomicAdd(hist + c, 1u);
          atomicAdd(hist + old, 0xFFFFFFFFu);
        }
      }
      __syncthreads();
    }
  }

  grid.sync();   // final idx + hist visible grid-wide

  // ======== Phase D: gather all rows from final idx (+stats, block 0) =====
  {
    const int gbase = (bid * 4 + w) * 32;
    for (int r = 0; r < 32; ++r) {
      const int row = gbase + r;
      const unsigned id = out_idx[row];
      v4f v = *(const v4f*)(cb + (size_t)id * DIMS + lane * 4);
      *(v4f*)(outz + (size_t)row * DIMS + lane * 4) = v;
    }
  }
  if (bid == 0) {
    float s = 0.f;
    for (int i = t; i < N_DICT; i += 256) {
      float p = (float)hist[i] * (1.0f / (float)N_ROWS);
      s += p * logf(p + 1e-10f);
    }
    #pragma unroll
    for (int d = 1; d < 64; d <<= 1) s += __shfl_xor(s, d);
    if ((t & 63) == 0) ls[t >> 6] = s;
    __syncthreads();
    if (t == 0) {
      float tot = ls[0] + ls[1] + ls[2] + ls[3];
      outz[16777216] = 0.0f;          // loss (eval)
      outz[16777217] = expf(-tot);    // perplexity
    }
  }
}

// ================= fallback path (v16, 4 dispatches) ======================
__global__ void k_prep(const float* __restrict__ cb, _Float16* __restrict__ swz_h,
                       _Float16* __restrict__ swz_l, float* __restrict__ cnA,
                       double* __restrict__ cnD,
                       unsigned* __restrict__ hist, unsigned* __restrict__ counters) {
  const int b = blockIdx.x, t = threadIdx.x;
  if (b == 0) {
    for (int i = t; i < N_DICT; i += 256) hist[i] = 0u;
    if (t == 0) { counters[0] = 0u; counters[1] = 0u; }
  }
  const int gid = b * 256 + t;
  const int col = gid >> 6;
  const int k0  = (gid & 63) * 4;
  v4f v = ((const v4f*)cb)[gid];
  v4h h, l;
  #pragma unroll
  for (int j = 0; j < 4; ++j) {
    h[j] = (_Float16)v[j];
    float r = v[j] - (float)h[j];
    l[j] = (_Float16)r;
  }
  const int c = col >> 6, t4 = (col >> 4) & 3, l15 = col & 15;
  const int kk = k0 >> 5, q = (k0 >> 3) & 3, j0 = k0 & 7;
  const size_t off = (size_t)(((c * 8 + kk) * 4 + t4) * 512 + (q * 16 + l15) * 8 + j0);
  *(v4h*)(swz_h + off) = h;
  *(v4h*)(swz_l + off) = l;
  const int lane = t & 63, w = t >> 6;
  const int row = b * 4 + w;
  v4f u = ((const v4f*)cb)[row * 64 + lane];
  double s = (double)u[0]*u[0] + (double)u[1]*u[1]
           + (double)u[2]*u[2] + (double)u[3]*u[3];
  #pragma unroll
  for (int d = 1; d < 64; d <<= 1) s += __shfl_xor(s, d);
  if (lane == 0) { cnA[row] = (float)s; cnD[row] = s; }
}

__launch_bounds__(256, 2)
__global__ void k_main(const float* __restrict__ z, const float* __restrict__ cb,
                       const _Float16* __restrict__ swz_h, const _Float16* __restrict__ swz_l,
                       const float* __restrict__ cnA,
                       float* __restrict__ outz,
                       unsigned* __restrict__ out_idx,
                       unsigned long long* __restrict__ list1,
                       unsigned* __restrict__ list2,
                       unsigned* __restrict__ hist,
                       unsigned* __restrict__ counters) {
  __shared__ __align__(16) char lds[2][32768];
  __shared__ float lds_cn[N_DICT];
  const int t = threadIdx.x, lane = t & 63, w = t >> 6;
  const int l15 = lane & 15, q = lane >> 4;
  const int waverow = (blockIdx.x * 4 + w) * 32;
  for (int i = t; i < N_DICT; i += 256) lds_cn[i] = cnA[i];
  v8h ah[2][8], al[2][8];
  #pragma unroll
  for (int m = 0; m < 2; ++m) {
    const float* zp = z + (size_t)(waverow + m * 16 + l15) * DIMS + q * 8;
    #pragma unroll
    for (int kk = 0; kk < 8; ++kk) {
      v4f f0 = *(const v4f*)(zp + kk * 32);
      v4f f1 = *(const v4f*)(zp + kk * 32 + 4);
      v8h hh, ll;
      #pragma unroll
      for (int j = 0; j < 4; ++j) {
        hh[j] = (_Float16)f0[j];
        float r = f0[j] - (float)hh[j];
        ll[j] = (_Float16)r;
        hh[4 + j] = (_Float16)f1[j];
        r = f1[j] - (float)hh[4 + j];
        ll[4 + j] = (_Float16)r;
      }
      ah[m][kk] = hh; al[m][kk] = ll;
    }
  }
  const int s0 = w * 8;
  const char* gsrc_base = (const char*)(s0 >= 16 ? swz_l : swz_h);
  float m1[8], m2[8], m3[8]; int c1[8], c2[8];
  #pragma unroll
  for (int s = 0; s < 8; ++s) {
    m1[s] = 1e30f; m2[s] = 1e30f; m3[s] = 1e30f; c1[s] = 0; c2[s] = 0;
  }
  #pragma unroll
  for (int i = 0; i < 8; ++i) {
    const int s = s0 + i, kk = (s >> 1) & 7, u = s & 1;
    gl_lds16(gsrc_base + (size_t)(kk * 4096 + u * 1024 + lane * 16), &lds[0][s * 1024]);
  }
  __syncthreads();
  for (int cc = 0; cc < 32; ++cc) {
    if (cc + 1 < 32) {
      const int n = cc + 1, c = n >> 1, half = n & 1;
      char* nbuf = lds[n & 1];
      #pragma unroll
      for (int i = 0; i < 8; ++i) {
        const int s = s0 + i, kk = (s >> 1) & 7, u = s & 1;
        gl_lds16(gsrc_base + (size_t)(c * 32768 + kk * 4096 + (2 * half + u) * 1024 + lane * 16),
                 nbuf + s * 1024);
      }
    }
    const char* buf = lds[cc & 1];
    const int c = cc >> 1, half = cc & 1;
    const int n0 = c * 64 + half * 32;
    float cn[2]; int colv[2];
    #pragma unroll
    for (int u = 0; u < 2; ++u) { colv[u] = n0 + u * 16 + l15; cn[u] = lds_cn[colv[u]]; }
    v4f acc[2][2];
    #pragma unroll
    for (int m = 0; m < 2; ++m)
      #pragma unroll
      for (int u = 0; u < 2; ++u) acc[m][u] = (v4f){0.f, 0.f, 0.f, 0.f};
    #pragma unroll
    for (int kk = 0; kk < 8; ++kk) {
      v8h b_h[2], b_l[2];
      #pragma unroll
      for (int u = 0; u < 2; ++u) b_h[u] = *(const v8h*)(buf + (kk * 2 + u) * 1024 + lane * 16);
      #pragma unroll
      for (int u = 0; u < 2; ++u) b_l[u] = *(const v8h*)(buf + 16384 + (kk * 2 + u) * 1024 + lane * 16);
      #pragma unroll
      for (int m = 0; m < 2; ++m) {
        #pragma unroll
        for (int u = 0; u < 2; ++u)
          acc[m][u] = __builtin_amdgcn_mfma_f32_16x16x32_f16(ah[m][kk], b_h[u], acc[m][u], 0, 0, 0);
        #pragma unroll
        for (int u = 0; u < 2; ++u)
          acc[m][u] = __builtin_amdgcn_mfma_f32_16x16x32_f16(al[m][kk], b_h[u], acc[m][u], 0, 0, 0);
        #pragma unroll
        for (int u = 0; u < 2; ++u)
          acc[m][u] = __builtin_amdgcn_mfma_f32_16x16x32_f16(ah[m][kk], b_l[u], acc[m][u], 0, 0, 0);
      }
    }
    #pragma unroll
    for (int m = 0; m < 2; ++m)
      #pragma unroll
      for (int u = 0; u < 2; ++u)
        #pragma unroll
        for (int r = 0; r < 4; ++r) {
          float cost = fmaf(acc[m][u][r], -2.0f, cn[u]);
          const int s = m * 4 + r;
          bool lt1 = cost < m1[s];
          bool lt2 = cost < m2[s];
          bool lt3 = cost < m3[s];
          m3[s] = lt2 ? m2[s] : (lt3 ? cost : m3[s]);
          m2[s] = lt1 ? m1[s] : (lt2 ? cost : m2[s]);
          c2[s] = lt1 ? c1[s] : (lt2 ? colv[u] : c2[s]);
          m1[s] = lt1 ? cost : m1[s];
          c1[s] = lt1 ? colv[u] : c1[s];
        }
    __syncthreads();
  }
  #pragma unroll
  for (int d = 1; d < 16; d <<= 1) {
    #pragma unroll
    for (int s = 0; s < 8; ++s) {
      float om1 = __shfl_xor(m1[s], d);
      float om2 = __shfl_xor(m2[s], d);
      float om3 = __shfl_xor(m3[s], d);
      int   oc1 = __shfl_xor(c1[s], d);
      int   oc2 = __shfl_xor(c2[s], d);
      bool take = (om1 < m1[s]) || (om1 == m1[s] && oc1 < c1[s]);
      float w1 = take ? om1 : m1[s];  int wc1 = take ? oc1 : c1[s];
      float w2 = take ? om2 : m2[s];  int wc2 = take ? oc2 : c2[s];
      float w3 = take ? om3 : m3[s];
      float l1 = take ? m1[s] : om1;  int lc1 = take ? c1[s] : oc1;
      float l2 = take ? m2[s] : om2;
      bool t2 = (l1 < w2) || (l1 == w2 && lc1 < wc2);
      m1[s] = w1; c1[s] = wc1;
      m2[s] = t2 ? l1 : w2;
      c2[s] = t2 ? lc1 : wc2;
      m3[s] = t2 ? fminf(w2, l2) : fminf(w3, l1);
    }
  }
  #pragma unroll
  for (int s = 0; s < 8; ++s) {
    const int m = s >> 2, r = s & 3;
    const int row = waverow + m * 16 + q * 4 + r;
    const unsigned id = (unsigned)c1[s];
    if (l15 == s) {
      out_idx[row] = id;
      atomicAdd(hist + id, 1u);
      if (m3[s] - m1[s] < MARGIN) {
        unsigned pos = atomicAdd(&counters[1], 1u);
        list2[pos] = (unsigned)row;
      } else if (m2[s] - m1[s] < MARGIN) {
        unsigned pos = atomicAdd(&counters[0], 1u);
        list1[pos] = (unsigned long long)row
                   | ((unsigned long long)id << 20)
                   | ((unsigned long long)(unsigned)c2[s] << 40);
      }
    }
    const float* src = cb + (size_t)id * DIMS + l15 * 16;
    float* dst = outz + (size_t)row * DIMS + l15 * 16;
    v4f t0 = *(const v4f*)(src + 0);
    v4f t1 = *(const v4f*)(src + 4);
    v4f t2v = *(const v4f*)(src + 8);
    v4f t3 = *(const v4f*)(src + 12);
    *(v4f*)(dst + 0) = t0;  *(v4f*)(dst + 4) = t1;
    *(v4f*)(dst + 8) = t2v; *(v4f*)(dst + 12) = t3;
  }
}

__global__ void k_resolve(const float* __restrict__ z, const float* __restrict__ cb,
                          const double* __restrict__ cnD,
                          const unsigned long long* __restrict__ list1,
                          const unsigned* __restrict__ list2,
                          const unsigned* __restrict__ counters,
                          unsigned* __restrict__ out_idx,
                          unsigned* __restrict__ hist,
                          float* __restrict__ outz) {
  const int t = threadIdx.x, lane = t & 63, w = t >> 6;
  if (blockIdx.x < 2048) {
    const unsigned count = counters[0];
    if (count == 0) return;
    const unsigned gw = blockIdx.x * 4 + w;
    const int half = lane >> 5, l5 = lane & 31;
    for (unsigned g = gw; g < count; g += 8192) {
      const unsigned long long e = list1[g];
      const unsigned row = (unsigned)(e & 0xFFFFFu);
      const int c1 = (int)((e >> 20) & 0x3FFu);
      const int c2 = (int)((e >> 40) & 0x3FFu);
      const int col = half ? c2 : c1;
      const float* cp = cb + (size_t)col * DIMS + l5 * 8;
      const float* zr = z + (size_t)row * DIMS + l5 * 8;
      v4f z0 = *(const v4f*)zr,  z1 = *(const v4f*)(zr + 4);
      v4f cc0 = *(const v4f*)cp, cc1 = *(const v4f*)(cp + 4);
      double a = (double)z0[0] * (double)cc0[0];
      a = fma((double)z0[1], (double)cc0[1], a);
      a = fma((double)z0[2], (double)cc0[2], a);
      a = fma((double)z0[3], (double)cc0[3], a);
      a = fma((double)z1[0], (double)cc1[0], a);
      a = fma((double)z1[1], (double)cc1[1], a);
      a = fma((double)z1[2], (double)cc1[2], a);
      a = fma((double)z1[3], (double)cc1[3], a);
      #pragma unroll
      for (int d = 1; d < 32; d <<= 1) a += __shfl_xor(a, d);
      double cost = cnD[col] - 2.0 * a;
      double oc = __shfl_xor(cost, 32);
      int win = 0;
      if (lane == 0) {
        bool take = (oc < cost) || (oc == cost && c2 < c1);
        win = take ? c2 : c1;
      }
      win = __shfl(win, 0);
      if (win != c1) {
        if (lane == 0) {
          out_idx[row] = (unsigned)win;
          atomicAdd(hist + win, 1u);
          atomicAdd(hist + c1, 0xFFFFFFFFu);
        }
        if (lane < 16) {
          const float* src = cb + (size_t)win * DIMS + lane * 16;
          float* dst = outz + (size_t)row * DIMS + lane * 16;
          v4f t0 = *(const v4f*)(src + 0);
          v4f t1 = *(const v4f*)(src + 4);
          v4f t2v = *(const v4f*)(src + 8);
          v4f t3 = *(const v4f*)(src + 12);
          *(v4f*)(dst + 0) = t0;  *(v4f*)(dst + 4) = t1;
          *(v4f*)(dst + 8) = t2v; *(v4f*)(dst + 12) = t3;
        }
      }
    }
  } else {
    const unsigned count = counters[1];
    if (count == 0) return;
    __shared__ double sc[4];
    __shared__ int scc[4];
    __shared__ int s_win;
    __shared__ unsigned s_old;
    for (unsigned g = blockIdx.x - 2048; g < count; g += 1024) {
      const unsigned row = list2[g];
      const float* zr = z + (size_t)row * DIMS;
      double best = 1e300; int bc = 1 << 30;
      for (int ci = w * 4; ci < w * 4 + 4; ++ci) {
        const int col = ci * 64 + lane;
        const float* cp = cb + (size_t)col * DIMS;
        double a0 = 0, a1 = 0, a2 = 0, a3 = 0, a4 = 0, a5 = 0, a6 = 0, a7 = 0;
        #pragma unroll 8
        for (int k = 0; k < DIMS; k += 8) {
          v4f z0 = *(const v4f*)(zr + k);
          v4f z1 = *(const v4f*)(zr + k + 4);
          v4f cc0 = *(const v4f*)(cp + k);
          v4f cc1 = *(const v4f*)(cp + k + 4);
          a0 = fma((double)z0[0], (double)cc0[0], a0);
          a1 = fma((double)z0[1], (double)cc0[1], a1);
          a2 = fma((double)z0[2], (double)cc0[2], a2);
          a3 = fma((double)z0[3], (double)cc0[3], a3);
          a4 = fma((double)z1[0], (double)cc1[0], a4);
          a5 = fma((double)z1[1], (double)cc1[1], a5);
          a6 = fma((double)z1[2], (double)cc1[2], a6);
          a7 = fma((double)z1[3], (double)cc1[3], a7);
        }
        double cost = cnD[col]
                    - 2.0 * (((a0 + a1) + (a2 + a3)) + ((a4 + a5) + (a6 + a7)));
        if (cost < best || (cost == best && col < bc)) { best = cost; bc = col; }
      }
      #pragma unroll
      for (int d = 1; d < 64; d <<= 1) {
        double ob = __shfl_xor(best, d);
        int    oc = __shfl_xor(bc, d);
        if (ob < best || (ob == best && oc < bc)) { best = ob; bc = oc; }
      }
      if (lane == 0) { sc[w] = best; scc[w] = bc; }
      __syncthreads();
      if (t == 0) {
        double b = sc[0]; int c = scc[0];
        #pragma unroll
        for (int i = 1; i < 4; ++i)
          if (sc[i] < b || (sc[i] == b && scc[i] < c)) { b = sc[i]; c = scc[i]; }
        unsigned old = out_idx[row];
        s_win = c; s_old = old;
        if ((unsigned)c != old) {
          out_idx[row] = (unsigned)c;
          atomicAdd(hist + c, 1u);
          atomicAdd(hist + old, 0xFFFFFFFFu);
        }
      }
      __syncthreads();
      if ((unsigned)s_win != s_old && t < 16) {
        const float* src = cb + (size_t)s_win * DIMS + t * 16;
        float* dst = outz + (size_t)row * DIMS + t * 16;
        v4f t0 = *(const v4f*)(src + 0);
        v4f t1 = *(const v4f*)(src + 4);
        v4f t2v = *(const v4f*)(src + 8);
        v4f t3 = *(const v4f*)(src + 12);
        *(v4f*)(dst + 0) = t0;  *(v4f*)(dst + 4) = t1;
        *(v4f*)(dst + 8) = t2v; *(v4f*)(dst + 12) = t3;
      }
      __syncthreads();
    }
  }
}

__global__ void k_stats(const unsigned* __restrict__ hist, float* __restrict__ out) {
  const int t = threadIdx.x;
  float s = 0.f;
  for (int i = t; i < N_DICT; i += 256) {
    float p = (float)hist[i] * (1.0f / (float)N_ROWS);
    s += p * logf(p + 1e-10f);
  }
  #pragma unroll
  for (int d = 1; d < 64; d <<= 1) s += __shfl_xor(s, d);
  __shared__ float ls[4];
  if ((t & 63) == 0) ls[t >> 6] = s;
  __syncthreads();
  if (t == 0) {
    float tot = ls[0] + ls[1] + ls[2] + ls[3];
    out[16777216] = 0.0f;
    out[16777217] = expf(-tot);
  }
}

extern "C" void kernel_launch(void* const* d_in, const int* in_sizes, int n_in,
                              void* d_out, int out_size, void* d_ws, size_t ws_size,
                              hipStream_t stream) {
  const float* z  = (const float*)d_in[0];
  const float* cb = (const float*)d_in[1];
  float* out = (float*)d_out;
  char* ws = (char*)d_ws;
  _Float16* swz_h            = (_Float16*)ws;                        // 512 KB
  _Float16* swz_l            = (_Float16*)(ws + 524288);             // 512 KB
  float*    cnA              = (float*)(ws + 1048576);               // 4 KB
  double*   cnD              = (double*)(ws + 1052672);              // 8 KB
  unsigned* idx              = (unsigned*)(ws + 1060864);            // 256 KB
  unsigned long long* list1  = (unsigned long long*)(ws + 1323008);  // 512 KB
  unsigned* list2            = (unsigned*)(ws + 1847296);            // 256 KB
  unsigned* hist             = (unsigned*)(ws + 2109440);            // 4 KB
  unsigned* counters         = (unsigned*)(ws + 2113536);            // 8 B

  void* args[] = {(void*)&z, (void*)&cb, (void*)&swz_h, (void*)&swz_l,
                  (void*)&cnA, (void*)&cnD, (void*)&out, (void*)&idx,
                  (void*)&list1, (void*)&list2, (void*)&hist, (void*)&counters};
  hipError_t err = hipLaunchCooperativeKernel((const void*)k_fused,
                                              dim3(512), dim3(256), args, 0, stream);
  if (err != hipSuccess) {
    // fallback: proven v16 4-dispatch path
    k_prep   <<<256,  256, 0, stream>>>(cb, swz_h, swz_l, cnA, cnD, hist, counters);
    k_main   <<<512,  256, 0, stream>>>(z, cb, swz_h, swz_l, cnA, out, idx, list1, list2, hist, counters);
    k_resolve<<<3072, 256, 0, stream>>>(z, cb, cnD, list1, list2, counters, idx, hist, out);
    k_stats  <<<1,    256, 0, stream>>>(hist, out);
  }
}

// Round 14
// 288.094 us; speedup vs baseline: 1.4114x; 1.4114x over previous
//
#include <hip/hip_runtime.h>
#include <hip/hip_bf16.h>
#include <stdint.h>

// WSVectorQuantizer: N=65536 rows (D=256) vs K=1024 codewords.
// v18: v16 (best, 243.9us) minus the k_stats dispatch: stats are computed by
// the LAST k_resolve block via a device-scope ticket (threadfence + atomic).
// v17 lesson: cooperative grid.sync costs ~50us/barrier at 512 blocks ->
// single-kernel fusion is dead; dispatch-count reduction must stay within
// the ordinary-launch model. k_prep/k_main byte-identical to v16.

typedef float  v4f __attribute__((ext_vector_type(4)));
typedef _Float16 v8h __attribute__((ext_vector_type(8)));
typedef _Float16 v4h __attribute__((ext_vector_type(4)));

#define N_ROWS 65536
#define N_DICT 1024
#define DIMS   256
#define MARGIN 4e-3f   // ~10x worst-tail of split-fp16 error (~4e-4)

__device__ __forceinline__ void gl_lds16(const void* g, void* l) {
  __builtin_amdgcn_global_load_lds(
      (const __attribute__((address_space(1))) unsigned int*)g,
      (__attribute__((address_space(3))) unsigned int*)l,
      16, 0, 0);
}

// ---------------- K1: prep ----------------
// codebook -> (h,l) split-fp16 stored in MFMA B-fragment order:
// off = ((c*8+kk)*4+t4)*512 + lane*8 + j, lane=q*16+l15 -> col=c*64+t4*16+l15,
// k = kk*32+q*8+j.  Also: cnA fp32 + cnD fp64 exact ||c||^2.
__global__ void k_prep(const float* __restrict__ cb, _Float16* __restrict__ swz_h,
                       _Float16* __restrict__ swz_l, float* __restrict__ cnA,
                       double* __restrict__ cnD,
                       unsigned* __restrict__ hist, unsigned* __restrict__ counters) {
  const int b = blockIdx.x, t = threadIdx.x;
  if (b == 0) {
    for (int i = t; i < N_DICT; i += 256) hist[i] = 0u;
    if (t == 0) { counters[0] = 0u; counters[1] = 0u; counters[2] = 0u; }
  }
  const int gid = b * 256 + t;                 // 65536 threads x 4 elems
  const int col = gid >> 6;
  const int k0  = (gid & 63) * 4;
  v4f v = ((const v4f*)cb)[gid];
  v4h h, l;
  #pragma unroll
  for (int j = 0; j < 4; ++j) {
    h[j] = (_Float16)v[j];
    float r = v[j] - (float)h[j];              // exact residual
    l[j] = (_Float16)r;                        // |err| <= 2^-22 |v|
  }
  const int c = col >> 6, t4 = (col >> 4) & 3, l15 = col & 15;
  const int kk = k0 >> 5, q = (k0 >> 3) & 3, j0 = k0 & 7;
  const size_t off = (size_t)(((c * 8 + kk) * 4 + t4) * 512 + (q * 16 + l15) * 8 + j0);
  *(v4h*)(swz_h + off) = h;
  *(v4h*)(swz_l + off) = l;
  // exact ||c||^2 (fp64 acc): one wave per codeword
  const int lane = t & 63, w = t >> 6;
  const int row = b * 4 + w;
  v4f u = ((const v4f*)cb)[row * 64 + lane];
  double s = (double)u[0]*u[0] + (double)u[1]*u[1]
           + (double)u[2]*u[2] + (double)u[3]*u[3];
  #pragma unroll
  for (int d = 1; d < 64; d <<= 1) s += __shfl_xor(s, d);
  if (lane == 0) { cnA[row] = (float)s; cnD[row] = s; }
}

// ---------------- K2: main split-fp16 MFMA argmin, m=2, 4-wave blocks ----------------
// 512 blocks x 256 thr (4 waves), 2 blocks/CU (68 KiB LDS). Wave owns 32
// rows; A h/l frags persistent. 32 chunks of 32 cols; 2x32KiB LDS dbuf +
// 4KiB cn; stage 1 ahead via global_load_lds; one __syncthreads per chunk.
// Per kk: 4 ds_read_b128, 12 MFMAs. Track top-3; fused epilogue writes
// out_idx + hist + z_q and classifies into pair/deep lists. (v16-proven.)
__launch_bounds__(256, 2)
__global__ void k_main(const float* __restrict__ z, const float* __restrict__ cb,
                       const _Float16* __restrict__ swz_h, const _Float16* __restrict__ swz_l,
                       const float* __restrict__ cnA,
                       float* __restrict__ outz,
                       unsigned* __restrict__ out_idx,
                       unsigned long long* __restrict__ list1,
                       unsigned* __restrict__ list2,
                       unsigned* __restrict__ hist,
                       unsigned* __restrict__ counters) {
  __shared__ __align__(16) char lds[2][32768];
  __shared__ float lds_cn[N_DICT];
  const int t = threadIdx.x, lane = t & 63, w = t >> 6;
  const int l15 = lane & 15, q = lane >> 4;
  const int waverow = (blockIdx.x * 4 + w) * 32;

  // cn -> LDS once (drained by the pre-loop __syncthreads)
  for (int i = t; i < N_DICT; i += 256) lds_cn[i] = cnA[i];

  // A fragments: lane holds z[waverow+m*16+l15][kk*32 + q*8 .. +8], split h/l
  v8h ah[2][8], al[2][8];
  #pragma unroll
  for (int m = 0; m < 2; ++m) {
    const float* zp = z + (size_t)(waverow + m * 16 + l15) * DIMS + q * 8;
    #pragma unroll
    for (int kk = 0; kk < 8; ++kk) {
      v4f f0 = *(const v4f*)(zp + kk * 32);
      v4f f1 = *(const v4f*)(zp + kk * 32 + 4);
      v8h hh, ll;
      #pragma unroll
      for (int j = 0; j < 4; ++j) {
        hh[j] = (_Float16)f0[j];
        float r = f0[j] - (float)hh[j];
        ll[j] = (_Float16)r;
        hh[4 + j] = (_Float16)f1[j];
        r = f1[j] - (float)hh[4 + j];
        ll[4 + j] = (_Float16)r;
      }
      ah[m][kk] = hh; al[m][kk] = ll;
    }
  }

  // Staging: wave w owns LDS streams s = w*8 .. w*8+7 (s = hl*16 + kk*2 + u).
  // Chunk n (32 cols): c = n>>1, half = n&1, t4 = 2*half + u.
  // Global src: hl_base + c*32768 + kk*4096 + (2*half+u)*1024 + lane*16.
  const int s0 = w * 8;
  const char* gsrc_base = (const char*)(s0 >= 16 ? swz_l : swz_h);

  // state s = m*4+r covers row = waverow + m*16 + q*4 + r
  float m1[8], m2[8], m3[8]; int c1[8], c2[8];
  #pragma unroll
  for (int s = 0; s < 8; ++s) {
    m1[s] = 1e30f; m2[s] = 1e30f; m3[s] = 1e30f; c1[s] = 0; c2[s] = 0;
  }

  // prologue: stage chunk 0 into lds[0]
  #pragma unroll
  for (int i = 0; i < 8; ++i) {
    const int s = s0 + i, kk = (s >> 1) & 7, u = s & 1;
    const char* gb = gsrc_base + (size_t)(kk * 4096 + u * 1024 + lane * 16);
    gl_lds16(gb, &lds[0][s * 1024]);
  }
  __syncthreads();   // drains prologue staging + lds_cn writes

  for (int cc = 0; cc < 32; ++cc) {
    // issue stage(cc+1) into lds[(cc+1)&1]; safe: end-of-(cc-1) barrier
    // came after all waves' reads of that buffer.
    if (cc + 1 < 32) {
      const int n = cc + 1, c = n >> 1, half = n & 1;
      char* nbuf = lds[n & 1];
      #pragma unroll
      for (int i = 0; i < 8; ++i) {
        const int s = s0 + i, kk = (s >> 1) & 7, u = s & 1;
        const char* gb = gsrc_base +
            (size_t)(c * 32768 + kk * 4096 + (2 * half + u) * 1024 + lane * 16);
        gl_lds16(gb, nbuf + s * 1024);
      }
    }

    const char* buf = lds[cc & 1];
    const int c = cc >> 1, half = cc & 1;
    const int n0 = c * 64 + half * 32;
    float cn[2]; int colv[2];
    #pragma unroll
    for (int u = 0; u < 2; ++u) {
      colv[u] = n0 + u * 16 + l15;
      cn[u] = lds_cn[colv[u]];              // LDS read: lgkm, not vmcnt
    }
    v4f acc[2][2];
    #pragma unroll
    for (int m = 0; m < 2; ++m)
      #pragma unroll
      for (int u = 0; u < 2; ++u) acc[m][u] = (v4f){0.f, 0.f, 0.f, 0.f};

    #pragma unroll
    for (int kk = 0; kk < 8; ++kk) {
      v8h b_h[2], b_l[2];
      #pragma unroll
      for (int u = 0; u < 2; ++u)
        b_h[u] = *(const v8h*)(buf + (kk * 2 + u) * 1024 + lane * 16);
      #pragma unroll
      for (int u = 0; u < 2; ++u)
        b_l[u] = *(const v8h*)(buf + 16384 + (kk * 2 + u) * 1024 + lane * 16);
      #pragma unroll
      for (int m = 0; m < 2; ++m) {
        #pragma unroll
        for (int u = 0; u < 2; ++u)
          acc[m][u] = __builtin_amdgcn_mfma_f32_16x16x32_f16(ah[m][kk], b_h[u], acc[m][u], 0, 0, 0);
        #pragma unroll
        for (int u = 0; u < 2; ++u)
          acc[m][u] = __builtin_amdgcn_mfma_f32_16x16x32_f16(al[m][kk], b_h[u], acc[m][u], 0, 0, 0);
        #pragma unroll
        for (int u = 0; u < 2; ++u)
          acc[m][u] = __builtin_amdgcn_mfma_f32_16x16x32_f16(ah[m][kk], b_l[u], acc[m][u], 0, 0, 0);
      }
    }
    // top-3 update (ordered: m3 uses old m2; m2/c2 use old m1/c1)
    #pragma unroll
    for (int m = 0; m < 2; ++m)
      #pragma unroll
      for (int u = 0; u < 2; ++u)
        #pragma unroll
        for (int r = 0; r < 4; ++r) {
          float cost = fmaf(acc[m][u][r], -2.0f, cn[u]);
          const int s = m * 4 + r;
          bool lt1 = cost < m1[s];
          bool lt2 = cost < m2[s];
          bool lt3 = cost < m3[s];
          m3[s] = lt2 ? m2[s] : (lt3 ? cost : m3[s]);
          m2[s] = lt1 ? m1[s] : (lt2 ? cost : m2[s]);
          c2[s] = lt1 ? c1[s] : (lt2 ? colv[u] : c2[s]);
          m1[s] = lt1 ? cost : m1[s];
          c1[s] = lt1 ? colv[u] : c1[s];
        }
    __syncthreads();  // stage(cc+1) landed; all waves done with buf
  }

  // butterfly merge of sorted top-3 lists over the 16 lanes sharing q
  #pragma unroll
  for (int d = 1; d < 16; d <<= 1) {
    #pragma unroll
    for (int s = 0; s < 8; ++s) {
      float om1 = __shfl_xor(m1[s], d);
      float om2 = __shfl_xor(m2[s], d);
      float om3 = __shfl_xor(m3[s], d);
      int   oc1 = __shfl_xor(c1[s], d);
      int   oc2 = __shfl_xor(c2[s], d);
      bool take = (om1 < m1[s]) || (om1 == m1[s] && oc1 < c1[s]);
      float w1 = take ? om1 : m1[s];  int wc1 = take ? oc1 : c1[s];
      float w2 = take ? om2 : m2[s];  int wc2 = take ? oc2 : c2[s];
      float w3 = take ? om3 : m3[s];
      float l1 = take ? m1[s] : om1;  int lc1 = take ? c1[s] : oc1;
      float l2 = take ? m2[s] : om2;
      bool t2 = (l1 < w2) || (l1 == w2 && lc1 < wc2);
      m1[s] = w1; c1[s] = wc1;
      m2[s] = t2 ? l1 : w2;
      c2[s] = t2 ? lc1 : wc2;
      m3[s] = t2 ? fminf(w2, l2) : fminf(w3, l1);
    }
  }
  // Fused epilogue (v15/v16-proven): all 16 lanes of a q-group agree on
  // every state. Per state: classify (lane l15==s), q-group writes z_q row.
  #pragma unroll
  for (int s = 0; s < 8; ++s) {
    const int m = s >> 2, r = s & 3;
    const int row = waverow + m * 16 + q * 4 + r;
    const unsigned id = (unsigned)c1[s];
    if (l15 == s) {
      out_idx[row] = id;
      atomicAdd(hist + id, 1u);
      if (m3[s] - m1[s] < MARGIN) {            // deep ambiguity: full scan
        unsigned pos = atomicAdd(&counters[1], 1u);
        list2[pos] = (unsigned)row;
      } else if (m2[s] - m1[s] < MARGIN) {     // only {c1,c2} can win
        unsigned pos = atomicAdd(&counters[0], 1u);
        list1[pos] = (unsigned long long)row
                   | ((unsigned long long)id << 20)
                   | ((unsigned long long)(unsigned)c2[s] << 40);
      }
    }
    // fused gather: q-group (16 lanes) copies cb[id] -> outz[row] (1 KiB)
    const float* src = cb + (size_t)id * DIMS + l15 * 16;
    float* dst = outz + (size_t)row * DIMS + l15 * 16;
    v4f t0 = *(const v4f*)(src + 0);
    v4f t1 = *(const v4f*)(src + 4);
    v4f t2v = *(const v4f*)(src + 8);
    v4f t3 = *(const v4f*)(src + 12);
    *(v4f*)(dst + 0) = t0;  *(v4f*)(dst + 4) = t1;
    *(v4f*)(dst + 8) = t2v; *(v4f*)(dst + 12) = t3;
  }
}

// ---------------- K3: exact fp64 resolve + last-block stats ----------------
// Pair blocks 0-2047, deep blocks 2048-3071; patches out_idx/hist/z_q.
// Every block then tickets counters[2]; the last block computes stats.
__global__ void k_resolve(const float* __restrict__ z, const float* __restrict__ cb,
                          const double* __restrict__ cnD,
                          const unsigned long long* __restrict__ list1,
                          const unsigned* __restrict__ list2,
                          unsigned* __restrict__ counters,
                          unsigned* __restrict__ out_idx,
                          unsigned* __restrict__ hist,
                          float* __restrict__ outz) {
  const int t = threadIdx.x, lane = t & 63, w = t >> 6;
  __shared__ unsigned s_ticket;
  if (blockIdx.x < 2048) {
    // pair: wave per row; lanes 0-31 cost(c1), lanes 32-63 cost(c2)
    const unsigned count = counters[0];
    const unsigned gw = blockIdx.x * 4 + w;
    const int half = lane >> 5, l5 = lane & 31;
    for (unsigned g = gw; g < count; g += 8192) {
      const unsigned long long e = list1[g];
      const unsigned row = (unsigned)(e & 0xFFFFFu);
      const int c1 = (int)((e >> 20) & 0x3FFu);
      const int c2 = (int)((e >> 40) & 0x3FFu);
      const int col = half ? c2 : c1;
      const float* cp = cb + (size_t)col * DIMS + l5 * 8;
      const float* zr = z + (size_t)row * DIMS + l5 * 8;
      v4f z0 = *(const v4f*)zr,  z1 = *(const v4f*)(zr + 4);
      v4f cc0 = *(const v4f*)cp, cc1 = *(const v4f*)(cp + 4);
      double a = (double)z0[0] * (double)cc0[0];
      a = fma((double)z0[1], (double)cc0[1], a);
      a = fma((double)z0[2], (double)cc0[2], a);
      a = fma((double)z0[3], (double)cc0[3], a);
      a = fma((double)z1[0], (double)cc1[0], a);
      a = fma((double)z1[1], (double)cc1[1], a);
      a = fma((double)z1[2], (double)cc1[2], a);
      a = fma((double)z1[3], (double)cc1[3], a);
      #pragma unroll
      for (int d = 1; d < 32; d <<= 1) a += __shfl_xor(a, d);
      double cost = cnD[col] - 2.0 * a;
      double oc = __shfl_xor(cost, 32);
      int win = 0;
      if (lane == 0) {
        bool take = (oc < cost) || (oc == cost && c2 < c1);   // np lowest-index
        win = take ? c2 : c1;
      }
      win = __shfl(win, 0);
      if (win != c1) {                       // k_main wrote c1; patch row
        if (lane == 0) {
          out_idx[row] = (unsigned)win;
          atomicAdd(hist + win, 1u);
          atomicAdd(hist + c1, 0xFFFFFFFFu);
        }
        if (lane < 16) {
          const float* src = cb + (size_t)win * DIMS + lane * 16;
          float* dst = outz + (size_t)row * DIMS + lane * 16;
          v4f t0 = *(const v4f*)(src + 0);
          v4f t1 = *(const v4f*)(src + 4);
          v4f t2v = *(const v4f*)(src + 8);
          v4f t3 = *(const v4f*)(src + 12);
          *(v4f*)(dst + 0) = t0;  *(v4f*)(dst + 4) = t1;
          *(v4f*)(dst + 8) = t2v; *(v4f*)(dst + 12) = t3;
        }
      }
    }
  } else {
    // deep: block per row; wave w covers ci = 4w..4w+3 (256 cols)
    const unsigned count = counters[1];
    __shared__ double sc[4];
    __shared__ int scc[4];
    __shared__ int s_win;
    __shared__ unsigned s_old;
    for (unsigned g = blockIdx.x - 2048; g < count; g += 1024) {
      const unsigned row = list2[g];
      const float* zr = z + (size_t)row * DIMS;
      double best = 1e300; int bc = 1 << 30;
      for (int ci = w * 4; ci < w * 4 + 4; ++ci) {
        const int col = ci * 64 + lane;
        const float* cp = cb + (size_t)col * DIMS;
        double a0 = 0, a1 = 0, a2 = 0, a3 = 0, a4 = 0, a5 = 0, a6 = 0, a7 = 0;
        #pragma unroll 8
        for (int k = 0; k < DIMS; k += 8) {
          v4f z0 = *(const v4f*)(zr + k);
          v4f z1 = *(const v4f*)(zr + k + 4);
          v4f cc0 = *(const v4f*)(cp + k);
          v4f cc1 = *(const v4f*)(cp + k + 4);
          a0 = fma((double)z0[0], (double)cc0[0], a0);
          a1 = fma((double)z0[1], (double)cc0[1], a1);
          a2 = fma((double)z0[2], (double)cc0[2], a2);
          a3 = fma((double)z0[3], (double)cc0[3], a3);
          a4 = fma((double)z1[0], (double)cc1[0], a4);
          a5 = fma((double)z1[1], (double)cc1[1], a5);
          a6 = fma((double)z1[2], (double)cc1[2], a6);
          a7 = fma((double)z1[3], (double)cc1[3], a7);
        }
        double cost = cnD[col]
                    - 2.0 * (((a0 + a1) + (a2 + a3)) + ((a4 + a5) + (a6 + a7)));
        if (cost < best || (cost == best && col < bc)) { best = cost; bc = col; }
      }
      #pragma unroll
      for (int d = 1; d < 64; d <<= 1) {
        double ob = __shfl_xor(best, d);
        int    oc = __shfl_xor(bc, d);
        if (ob < best || (ob == best && oc < bc)) { best = ob; bc = oc; }
      }
      if (lane == 0) { sc[w] = best; scc[w] = bc; }
      __syncthreads();
      if (t == 0) {
        double b = sc[0]; int c = scc[0];
        #pragma unroll
        for (int i = 1; i < 4; ++i)
          if (sc[i] < b || (sc[i] == b && scc[i] < c)) { b = sc[i]; c = scc[i]; }
        unsigned old = out_idx[row];
        s_win = c; s_old = old;
        if ((unsigned)c != old) {
          out_idx[row] = (unsigned)c;
          atomicAdd(hist + c, 1u);
          atomicAdd(hist + old, 0xFFFFFFFFu);
        }
      }
      __syncthreads();
      if ((unsigned)s_win != s_old && t < 16) {
        const float* src = cb + (size_t)s_win * DIMS + t * 16;
        float* dst = outz + (size_t)row * DIMS + t * 16;
        v4f t0 = *(const v4f*)(src + 0);
        v4f t1 = *(const v4f*)(src + 4);
        v4f t2v = *(const v4f*)(src + 8);
        v4f t3 = *(const v4f*)(src + 12);
        *(v4f*)(dst + 0) = t0;  *(v4f*)(dst + 4) = t1;
        *(v4f*)(dst + 8) = t2v; *(v4f*)(dst + 12) = t3;
      }
      __syncthreads();
    }
  }

  // ---- last-block-done stats (replaces the k_stats dispatch) ----
  __syncthreads();                 // all block work (incl. atomics issued)
  if (t == 0) {
    __threadfence();               // device-scope: hist/idx/z_q visible
    s_ticket = atomicAdd(&counters[2], 1u);
  }
  __syncthreads();
  if (s_ticket == (unsigned)(gridDim.x - 1)) {   // last block: hist is final
    float s = 0.f;
    for (int i = t; i < N_DICT; i += 256) {
      float p = (float)hist[i] * (1.0f / (float)N_ROWS);
      s += p * logf(p + 1e-10f);
    }
    #pragma unroll
    for (int d = 1; d < 64; d <<= 1) s += __shfl_xor(s, d);
    __shared__ float ls[4];
    if ((t & 63) == 0) ls[t >> 6] = s;
    __syncthreads();
    if (t == 0) {
      float tot = ls[0] + ls[1] + ls[2] + ls[3];
      outz[16777216] = 0.0f;          // loss (eval)
      outz[16777217] = expf(-tot);    // perplexity
    }
  }
}

extern "C" void kernel_launch(void* const* d_in, const int* in_sizes, int n_in,
                              void* d_out, int out_size, void* d_ws, size_t ws_size,
                              hipStream_t stream) {
  const float* z  = (const float*)d_in[0];
  const float* cb = (const float*)d_in[1];
  float* out = (float*)d_out;
  char* ws = (char*)d_ws;
  _Float16* swz_h            = (_Float16*)ws;                        // 512 KB
  _Float16* swz_l            = (_Float16*)(ws + 524288);             // 512 KB
  float*    cnA              = (float*)(ws + 1048576);               // 4 KB
  double*   cnD              = (double*)(ws + 1052672);              // 8 KB
  unsigned* idx              = (unsigned*)(ws + 1060864);            // 256 KB
  unsigned long long* list1  = (unsigned long long*)(ws + 1323008);  // 512 KB
  unsigned* list2            = (unsigned*)(ws + 1847296);            // 256 KB
  unsigned* hist             = (unsigned*)(ws + 2109440);            // 4 KB
  unsigned* counters         = (unsigned*)(ws + 2113536);            // 12 B

  k_prep   <<<256,  256, 0, stream>>>(cb, swz_h, swz_l, cnA, cnD, hist, counters);
  k_main   <<<512,  256, 0, stream>>>(z, cb, swz_h, swz_l, cnA, out, idx, list1, list2, hist, counters);
  k_resolve<<<3072, 256, 0, stream>>>(z, cb, cnD, list1, list2, counters, idx, hist, out);
}

// Round 15
// 239.497 us; speedup vs baseline: 1.6978x; 1.2029x over previous
//
#include <hip/hip_runtime.h>
#include <hip/hip_bf16.h>
#include <stdint.h>

// WSVectorQuantizer: N=65536 rows (D=256) vs K=1024 codewords.
// v19 = v16 verbatim (best-measured: 243.9us). v18's ticket-stats fusion
// reverted: it coincided with a regression and demonstrated +-15% run
// variance on byte-identical k_main (155 vs 181us), so small dispatch-count
// levers are below the noise floor. v16 = v13's k_main (512x256, 2 blocks/CU,
// LDS dbuf, simple per-chunk sync) + fused gather/hist/classify epilogue +
// patching k_resolve + k_stats.

typedef float  v4f __attribute__((ext_vector_type(4)));
typedef _Float16 v8h __attribute__((ext_vector_type(8)));
typedef _Float16 v4h __attribute__((ext_vector_type(4)));

#define N_ROWS 65536
#define N_DICT 1024
#define DIMS   256
#define MARGIN 4e-3f   // ~10x worst-tail of split-fp16 error (~4e-4)

__device__ __forceinline__ void gl_lds16(const void* g, void* l) {
  __builtin_amdgcn_global_load_lds(
      (const __attribute__((address_space(1))) unsigned int*)g,
      (__attribute__((address_space(3))) unsigned int*)l,
      16, 0, 0);
}

// ---------------- K1: prep ----------------
// codebook -> (h,l) split-fp16 stored in MFMA B-fragment order:
// off = ((c*8+kk)*4+t4)*512 + lane*8 + j, lane=q*16+l15 -> col=c*64+t4*16+l15,
// k = kk*32+q*8+j.  Also: cnA fp32 + cnD fp64 exact ||c||^2.
__global__ void k_prep(const float* __restrict__ cb, _Float16* __restrict__ swz_h,
                       _Float16* __restrict__ swz_l, float* __restrict__ cnA,
                       double* __restrict__ cnD,
                       unsigned* __restrict__ hist, unsigned* __restrict__ counters) {
  const int b = blockIdx.x, t = threadIdx.x;
  if (b == 0) {
    for (int i = t; i < N_DICT; i += 256) hist[i] = 0u;
    if (t == 0) { counters[0] = 0u; counters[1] = 0u; }
  }
  const int gid = b * 256 + t;                 // 65536 threads x 4 elems
  const int col = gid >> 6;
  const int k0  = (gid & 63) * 4;
  v4f v = ((const v4f*)cb)[gid];
  v4h h, l;
  #pragma unroll
  for (int j = 0; j < 4; ++j) {
    h[j] = (_Float16)v[j];
    float r = v[j] - (float)h[j];              // exact residual
    l[j] = (_Float16)r;                        // |err| <= 2^-22 |v|
  }
  const int c = col >> 6, t4 = (col >> 4) & 3, l15 = col & 15;
  const int kk = k0 >> 5, q = (k0 >> 3) & 3, j0 = k0 & 7;
  const size_t off = (size_t)(((c * 8 + kk) * 4 + t4) * 512 + (q * 16 + l15) * 8 + j0);
  *(v4h*)(swz_h + off) = h;
  *(v4h*)(swz_l + off) = l;
  // exact ||c||^2 (fp64 acc): one wave per codeword
  const int lane = t & 63, w = t >> 6;
  const int row = b * 4 + w;
  v4f u = ((const v4f*)cb)[row * 64 + lane];
  double s = (double)u[0]*u[0] + (double)u[1]*u[1]
           + (double)u[2]*u[2] + (double)u[3]*u[3];
  #pragma unroll
  for (int d = 1; d < 64; d <<= 1) s += __shfl_xor(s, d);
  if (lane == 0) { cnA[row] = (float)s; cnD[row] = s; }
}

// ---------------- K2: main split-fp16 MFMA argmin, m=2, 4-wave blocks ----------------
// 512 blocks x 256 thr (4 waves), 2 blocks/CU (68 KiB LDS). Wave owns 32
// rows; A h/l frags persistent. 32 chunks of 32 cols; 2x32KiB LDS dbuf +
// 4KiB cn; stage 1 ahead via global_load_lds; one __syncthreads per chunk.
// Per kk: 4 ds_read_b128, 12 MFMAs. Track top-3; fused epilogue writes
// out_idx + hist + z_q and classifies into pair/deep lists.
__launch_bounds__(256, 2)
__global__ void k_main(const float* __restrict__ z, const float* __restrict__ cb,
                       const _Float16* __restrict__ swz_h, const _Float16* __restrict__ swz_l,
                       const float* __restrict__ cnA,
                       float* __restrict__ outz,
                       unsigned* __restrict__ out_idx,
                       unsigned long long* __restrict__ list1,
                       unsigned* __restrict__ list2,
                       unsigned* __restrict__ hist,
                       unsigned* __restrict__ counters) {
  __shared__ __align__(16) char lds[2][32768];
  __shared__ float lds_cn[N_DICT];
  const int t = threadIdx.x, lane = t & 63, w = t >> 6;
  const int l15 = lane & 15, q = lane >> 4;
  const int waverow = (blockIdx.x * 4 + w) * 32;

  // cn -> LDS once (drained by the pre-loop __syncthreads)
  for (int i = t; i < N_DICT; i += 256) lds_cn[i] = cnA[i];

  // A fragments: lane holds z[waverow+m*16+l15][kk*32 + q*8 .. +8], split h/l
  v8h ah[2][8], al[2][8];
  #pragma unroll
  for (int m = 0; m < 2; ++m) {
    const float* zp = z + (size_t)(waverow + m * 16 + l15) * DIMS + q * 8;
    #pragma unroll
    for (int kk = 0; kk < 8; ++kk) {
      v4f f0 = *(const v4f*)(zp + kk * 32);
      v4f f1 = *(const v4f*)(zp + kk * 32 + 4);
      v8h hh, ll;
      #pragma unroll
      for (int j = 0; j < 4; ++j) {
        hh[j] = (_Float16)f0[j];
        float r = f0[j] - (float)hh[j];
        ll[j] = (_Float16)r;
        hh[4 + j] = (_Float16)f1[j];
        r = f1[j] - (float)hh[4 + j];
        ll[4 + j] = (_Float16)r;
      }
      ah[m][kk] = hh; al[m][kk] = ll;
    }
  }

  // Staging: wave w owns LDS streams s = w*8 .. w*8+7 (s = hl*16 + kk*2 + u).
  // Chunk n (32 cols): c = n>>1, half = n&1, t4 = 2*half + u.
  // Global src: hl_base + c*32768 + kk*4096 + (2*half+u)*1024 + lane*16.
  const int s0 = w * 8;
  const char* gsrc_base = (const char*)(s0 >= 16 ? swz_l : swz_h);

  // state s = m*4+r covers row = waverow + m*16 + q*4 + r
  float m1[8], m2[8], m3[8]; int c1[8], c2[8];
  #pragma unroll
  for (int s = 0; s < 8; ++s) {
    m1[s] = 1e30f; m2[s] = 1e30f; m3[s] = 1e30f; c1[s] = 0; c2[s] = 0;
  }

  // prologue: stage chunk 0 into lds[0]
  #pragma unroll
  for (int i = 0; i < 8; ++i) {
    const int s = s0 + i, kk = (s >> 1) & 7, u = s & 1;
    const char* gb = gsrc_base + (size_t)(kk * 4096 + u * 1024 + lane * 16);
    gl_lds16(gb, &lds[0][s * 1024]);
  }
  __syncthreads();   // drains prologue staging + lds_cn writes

  for (int cc = 0; cc < 32; ++cc) {
    // issue stage(cc+1) into lds[(cc+1)&1]; safe: end-of-(cc-1) barrier
    // came after all waves' reads of that buffer.
    if (cc + 1 < 32) {
      const int n = cc + 1, c = n >> 1, half = n & 1;
      char* nbuf = lds[n & 1];
      #pragma unroll
      for (int i = 0; i < 8; ++i) {
        const int s = s0 + i, kk = (s >> 1) & 7, u = s & 1;
        const char* gb = gsrc_base +
            (size_t)(c * 32768 + kk * 4096 + (2 * half + u) * 1024 + lane * 16);
        gl_lds16(gb, nbuf + s * 1024);
      }
    }

    const char* buf = lds[cc & 1];
    const int c = cc >> 1, half = cc & 1;
    const int n0 = c * 64 + half * 32;
    float cn[2]; int colv[2];
    #pragma unroll
    for (int u = 0; u < 2; ++u) {
      colv[u] = n0 + u * 16 + l15;
      cn[u] = lds_cn[colv[u]];              // LDS read: lgkm, not vmcnt
    }
    v4f acc[2][2];
    #pragma unroll
    for (int m = 0; m < 2; ++m)
      #pragma unroll
      for (int u = 0; u < 2; ++u) acc[m][u] = (v4f){0.f, 0.f, 0.f, 0.f};

    #pragma unroll
    for (int kk = 0; kk < 8; ++kk) {
      v8h b_h[2], b_l[2];
      #pragma unroll
      for (int u = 0; u < 2; ++u)
        b_h[u] = *(const v8h*)(buf + (kk * 2 + u) * 1024 + lane * 16);
      #pragma unroll
      for (int u = 0; u < 2; ++u)
        b_l[u] = *(const v8h*)(buf + 16384 + (kk * 2 + u) * 1024 + lane * 16);
      #pragma unroll
      for (int m = 0; m < 2; ++m) {
        #pragma unroll
        for (int u = 0; u < 2; ++u)
          acc[m][u] = __builtin_amdgcn_mfma_f32_16x16x32_f16(ah[m][kk], b_h[u], acc[m][u], 0, 0, 0);
        #pragma unroll
        for (int u = 0; u < 2; ++u)
          acc[m][u] = __builtin_amdgcn_mfma_f32_16x16x32_f16(al[m][kk], b_h[u], acc[m][u], 0, 0, 0);
        #pragma unroll
        for (int u = 0; u < 2; ++u)
          acc[m][u] = __builtin_amdgcn_mfma_f32_16x16x32_f16(ah[m][kk], b_l[u], acc[m][u], 0, 0, 0);
      }
    }
    // top-3 update (ordered: m3 uses old m2; m2/c2 use old m1/c1)
    #pragma unroll
    for (int m = 0; m < 2; ++m)
      #pragma unroll
      for (int u = 0; u < 2; ++u)
        #pragma unroll
        for (int r = 0; r < 4; ++r) {
          float cost = fmaf(acc[m][u][r], -2.0f, cn[u]);
          const int s = m * 4 + r;
          bool lt1 = cost < m1[s];
          bool lt2 = cost < m2[s];
          bool lt3 = cost < m3[s];
          m3[s] = lt2 ? m2[s] : (lt3 ? cost : m3[s]);
          m2[s] = lt1 ? m1[s] : (lt2 ? cost : m2[s]);
          c2[s] = lt1 ? c1[s] : (lt2 ? colv[u] : c2[s]);
          m1[s] = lt1 ? cost : m1[s];
          c1[s] = lt1 ? colv[u] : c1[s];
        }
    __syncthreads();  // stage(cc+1) landed; all waves done with buf
  }

  // butterfly merge of sorted top-3 lists over the 16 lanes sharing q
  #pragma unroll
  for (int d = 1; d < 16; d <<= 1) {
    #pragma unroll
    for (int s = 0; s < 8; ++s) {
      float om1 = __shfl_xor(m1[s], d);
      float om2 = __shfl_xor(m2[s], d);
      float om3 = __shfl_xor(m3[s], d);
      int   oc1 = __shfl_xor(c1[s], d);
      int   oc2 = __shfl_xor(c2[s], d);
      bool take = (om1 < m1[s]) || (om1 == m1[s] && oc1 < c1[s]);
      float w1 = take ? om1 : m1[s];  int wc1 = take ? oc1 : c1[s];
      float w2 = take ? om2 : m2[s];  int wc2 = take ? oc2 : c2[s];
      float w3 = take ? om3 : m3[s];
      float l1 = take ? m1[s] : om1;  int lc1 = take ? c1[s] : oc1;
      float l2 = take ? m2[s] : om2;
      bool t2 = (l1 < w2) || (l1 == w2 && lc1 < wc2);
      m1[s] = w1; c1[s] = wc1;
      m2[s] = t2 ? l1 : w2;
      c2[s] = t2 ? lc1 : wc2;
      m3[s] = t2 ? fminf(w2, l2) : fminf(w3, l1);
    }
  }
  // Fused epilogue (v15-proven): all 16 lanes of a q-group agree on every
  // state. Per state: classify (lane l15==s), then q-group writes z_q row.
  #pragma unroll
  for (int s = 0; s < 8; ++s) {
    const int m = s >> 2, r = s & 3;
    const int row = waverow + m * 16 + q * 4 + r;
    const unsigned id = (unsigned)c1[s];
    if (l15 == s) {
      out_idx[row] = id;
      atomicAdd(hist + id, 1u);
      if (m3[s] - m1[s] < MARGIN) {            // deep ambiguity: full scan
        unsigned pos = atomicAdd(&counters[1], 1u);
        list2[pos] = (unsigned)row;
      } else if (m2[s] - m1[s] < MARGIN) {     // only {c1,c2} can win
        unsigned pos = atomicAdd(&counters[0], 1u);
        list1[pos] = (unsigned long long)row
                   | ((unsigned long long)id << 20)
                   | ((unsigned long long)(unsigned)c2[s] << 40);
      }
    }
    // fused gather: q-group (16 lanes) copies cb[id] -> outz[row] (1 KiB)
    const float* src = cb + (size_t)id * DIMS + l15 * 16;
    float* dst = outz + (size_t)row * DIMS + l15 * 16;
    v4f t0 = *(const v4f*)(src + 0);
    v4f t1 = *(const v4f*)(src + 4);
    v4f t2v = *(const v4f*)(src + 8);
    v4f t3 = *(const v4f*)(src + 12);
    *(v4f*)(dst + 0) = t0;  *(v4f*)(dst + 4) = t1;
    *(v4f*)(dst + 8) = t2v; *(v4f*)(dst + 12) = t3;
  }
}

// ---------------- K3: exact fp64 resolve (pair blocks 0-2047, deep 2048-3071) ----------------
// Patches out_idx, hist, and the z_q row for flipped rows. (v15-proven.)
__global__ void k_resolve(const float* __restrict__ z, const float* __restrict__ cb,
                          const double* __restrict__ cnD,
                          const unsigned long long* __restrict__ list1,
                          const unsigned* __restrict__ list2,
                          const unsigned* __restrict__ counters,
                          unsigned* __restrict__ out_idx,
                          unsigned* __restrict__ hist,
                          float* __restrict__ outz) {
  const int t = threadIdx.x, lane = t & 63, w = t >> 6;
  if (blockIdx.x < 2048) {
    // pair: wave per row; lanes 0-31 cost(c1), lanes 32-63 cost(c2)
    const unsigned count = counters[0];
    if (count == 0) return;
    const unsigned gw = blockIdx.x * 4 + w;
    const int half = lane >> 5, l5 = lane & 31;
    for (unsigned g = gw; g < count; g += 8192) {
      const unsigned long long e = list1[g];
      const unsigned row = (unsigned)(e & 0xFFFFFu);
      const int c1 = (int)((e >> 20) & 0x3FFu);
      const int c2 = (int)((e >> 40) & 0x3FFu);
      const int col = half ? c2 : c1;
      const float* cp = cb + (size_t)col * DIMS + l5 * 8;
      const float* zr = z + (size_t)row * DIMS + l5 * 8;
      v4f z0 = *(const v4f*)zr,  z1 = *(const v4f*)(zr + 4);
      v4f cc0 = *(const v4f*)cp, cc1 = *(const v4f*)(cp + 4);
      double a = (double)z0[0] * (double)cc0[0];
      a = fma((double)z0[1], (double)cc0[1], a);
      a = fma((double)z0[2], (double)cc0[2], a);
      a = fma((double)z0[3], (double)cc0[3], a);
      a = fma((double)z1[0], (double)cc1[0], a);
      a = fma((double)z1[1], (double)cc1[1], a);
      a = fma((double)z1[2], (double)cc1[2], a);
      a = fma((double)z1[3], (double)cc1[3], a);
      #pragma unroll
      for (int d = 1; d < 32; d <<= 1) a += __shfl_xor(a, d);
      double cost = cnD[col] - 2.0 * a;
      double oc = __shfl_xor(cost, 32);
      int win = 0;
      if (lane == 0) {
        bool take = (oc < cost) || (oc == cost && c2 < c1);   // np lowest-index
        win = take ? c2 : c1;
      }
      win = __shfl(win, 0);
      if (win != c1) {                       // k_main wrote c1; patch row
        if (lane == 0) {
          out_idx[row] = (unsigned)win;
          atomicAdd(hist + win, 1u);
          atomicAdd(hist + c1, 0xFFFFFFFFu);
        }
        if (lane < 16) {
          const float* src = cb + (size_t)win * DIMS + lane * 16;
          float* dst = outz + (size_t)row * DIMS + lane * 16;
          v4f t0 = *(const v4f*)(src + 0);
          v4f t1 = *(const v4f*)(src + 4);
          v4f t2v = *(const v4f*)(src + 8);
          v4f t3 = *(const v4f*)(src + 12);
          *(v4f*)(dst + 0) = t0;  *(v4f*)(dst + 4) = t1;
          *(v4f*)(dst + 8) = t2v; *(v4f*)(dst + 12) = t3;
        }
      }
    }
  } else {
    // deep: block per row; wave w covers ci = 4w..4w+3 (256 cols)
    const unsigned count = counters[1];
    if (count == 0) return;
    __shared__ double sc[4];
    __shared__ int scc[4];
    __shared__ int s_win;
    __shared__ unsigned s_old;
    for (unsigned g = blockIdx.x - 2048; g < count; g += 1024) {
      const unsigned row = list2[g];
      const float* zr = z + (size_t)row * DIMS;
      double best = 1e300; int bc = 1 << 30;
      for (int ci = w * 4; ci < w * 4 + 4; ++ci) {
        const int col = ci * 64 + lane;
        const float* cp = cb + (size_t)col * DIMS;
        double a0 = 0, a1 = 0, a2 = 0, a3 = 0, a4 = 0, a5 = 0, a6 = 0, a7 = 0;
        #pragma unroll 8
        for (int k = 0; k < DIMS; k += 8) {
          v4f z0 = *(const v4f*)(zr + k);
          v4f z1 = *(const v4f*)(zr + k + 4);
          v4f cc0 = *(const v4f*)(cp + k);
          v4f cc1 = *(const v4f*)(cp + k + 4);
          a0 = fma((double)z0[0], (double)cc0[0], a0);
          a1 = fma((double)z0[1], (double)cc0[1], a1);
          a2 = fma((double)z0[2], (double)cc0[2], a2);
          a3 = fma((double)z0[3], (double)cc0[3], a3);
          a4 = fma((double)z1[0], (double)cc1[0], a4);
          a5 = fma((double)z1[1], (double)cc1[1], a5);
          a6 = fma((double)z1[2], (double)cc1[2], a6);
          a7 = fma((double)z1[3], (double)cc1[3], a7);
        }
        double cost = cnD[col]
                    - 2.0 * (((a0 + a1) + (a2 + a3)) + ((a4 + a5) + (a6 + a7)));
        if (cost < best || (cost == best && col < bc)) { best = cost; bc = col; }
      }
      #pragma unroll
      for (int d = 1; d < 64; d <<= 1) {
        double ob = __shfl_xor(best, d);
        int    oc = __shfl_xor(bc, d);
        if (ob < best || (ob == best && oc < bc)) { best = ob; bc = oc; }
      }
      if (lane == 0) { sc[w] = best; scc[w] = bc; }
      __syncthreads();
      if (t == 0) {
        double b = sc[0]; int c = scc[0];
        #pragma unroll
        for (int i = 1; i < 4; ++i)
          if (sc[i] < b || (sc[i] == b && scc[i] < c)) { b = sc[i]; c = scc[i]; }
        unsigned old = out_idx[row];
        s_win = c; s_old = old;
        if ((unsigned)c != old) {
          out_idx[row] = (unsigned)c;
          atomicAdd(hist + c, 1u);
          atomicAdd(hist + old, 0xFFFFFFFFu);
        }
      }
      __syncthreads();
      if ((unsigned)s_win != s_old && t < 16) {
        const float* src = cb + (size_t)s_win * DIMS + t * 16;
        float* dst = outz + (size_t)row * DIMS + t * 16;
        v4f t0 = *(const v4f*)(src + 0);
        v4f t1 = *(const v4f*)(src + 4);
        v4f t2v = *(const v4f*)(src + 8);
        v4f t3 = *(const v4f*)(src + 12);
        *(v4f*)(dst + 0) = t0;  *(v4f*)(dst + 4) = t1;
        *(v4f*)(dst + 8) = t2v; *(v4f*)(dst + 12) = t3;
      }
      __syncthreads();
    }
  }
}

// ---------------- K5: loss + perplexity ----------------
__global__ void k_stats(const unsigned* __restrict__ hist, float* __restrict__ out) {
  const int t = threadIdx.x;
  float s = 0.f;
  for (int i = t; i < N_DICT; i += 256) {
    float p = (float)hist[i] * (1.0f / (float)N_ROWS);
    s += p * logf(p + 1e-10f);
  }
  #pragma unroll
  for (int d = 1; d < 64; d <<= 1) s += __shfl_xor(s, d);
  __shared__ float ls[4];
  if ((t & 63) == 0) ls[t >> 6] = s;
  __syncthreads();
  if (t == 0) {
    float tot = ls[0] + ls[1] + ls[2] + ls[3];
    out[16777216] = 0.0f;          // loss (eval)
    out[16777217] = expf(-tot);    // perplexity
  }
}

extern "C" void kernel_launch(void* const* d_in, const int* in_sizes, int n_in,
                              void* d_out, int out_size, void* d_ws, size_t ws_size,
                              hipStream_t stream) {
  const float* z  = (const float*)d_in[0];
  const float* cb = (const float*)d_in[1];
  float* out = (float*)d_out;
  char* ws = (char*)d_ws;
  _Float16* swz_h            = (_Float16*)ws;                        // 512 KB
  _Float16* swz_l            = (_Float16*)(ws + 524288);             // 512 KB
  float*    cnA              = (float*)(ws + 1048576);               // 4 KB
  double*   cnD              = (double*)(ws + 1052672);              // 8 KB
  unsigned* idx              = (unsigned*)(ws + 1060864);            // 256 KB
  unsigned long long* list1  = (unsigned long long*)(ws + 1323008);  // 512 KB
  unsigned* list2            = (unsigned*)(ws + 1847296);            // 256 KB
  unsigned* hist             = (unsigned*)(ws + 2109440);            // 4 KB
  unsigned* counters         = (unsigned*)(ws + 2113536);            // 8 B

  k_prep   <<<256,  256, 0, stream>>>(cb, swz_h, swz_l, cnA, cnD, hist, counters);
  k_main   <<<512,  256, 0, stream>>>(z, cb, swz_h, swz_l, cnA, out, idx, list1, list2, hist, counters);
  k_resolve<<<3072, 256, 0, stream>>>(z, cb, cnD, list1, list2, counters, idx, hist, out);
  k_stats  <<<1,    256, 0, stream>>>(hist, out);
}